// Round 13
// baseline (594.636 us; speedup 1.0000x reference)
//
#include <hip/hip_runtime.h>
#include <cstdint>
#include <cstddef>

#define N_NODES 100000
#define N_EDGES 1600000
#define IN_DIM  64
#define HID     128
#define NCLS    18
#define BATCH   8
#define TOPK    5000
#define NPER    12500   // N_NODES / BATCH
#define SORTN   16384   // next pow2 >= NPER
#define SORTC   2048    // LDS-local chunk for stage-1 bitonic

#define BSHIFT  9                      // bucket = node >> 9 (512 nodes per bucket)
#define BNODES  (1 << BSHIFT)
#define NBUCK   ((N_NODES + BNODES - 1) / BNODES)   // 196
#define CHUNK   8192                   // edges per block in binning kernels

// ---------------- bucket-level counting (LDS-privatized) ----------------

__global__ __launch_bounds__(256) void k_bcount(const int* __restrict__ src,
                                                const int* __restrict__ dst,
                                                int* __restrict__ bcntS,
                                                int* __restrict__ bcntD) {
    __shared__ int cs[NBUCK], cd[NBUCK];
    for (int b = threadIdx.x; b < NBUCK; b += 256) { cs[b] = 0; cd[b] = 0; }
    __syncthreads();
    const int base = blockIdx.x * CHUNK;
    const int end  = min(base + CHUNK, N_EDGES);
    for (int e = base + threadIdx.x; e < end; e += 256) {
        atomicAdd(&cs[src[e] >> BSHIFT], 1);
        atomicAdd(&cd[dst[e] >> BSHIFT], 1);
    }
    __syncthreads();
    for (int b = threadIdx.x; b < NBUCK; b += 256) {
        if (cs[b]) atomicAdd(&bcntS[b], cs[b]);
        if (cd[b]) atomicAdd(&bcntD[b], cd[b]);
    }
}

__global__ void k_bscan(const int* __restrict__ bcntS, const int* __restrict__ bcntD,
                        int* __restrict__ baseS, int* __restrict__ baseD,
                        int* __restrict__ curS, int* __restrict__ curD) {
    if (threadIdx.x == 0 && blockIdx.x == 0) {
        int rs = 0, rd = 0;
        for (int b = 0; b < NBUCK; ++b) {
            baseS[b] = rs; curS[b] = rs; rs += bcntS[b];
            baseD[b] = rd; curD[b] = rd; rd += bcntD[b];
        }
        baseS[NBUCK] = rs; baseD[NBUCK] = rd;
    }
}

// ---------------- merged binned edge placement (dst-bin AND src-bin) --------

__global__ __launch_bounds__(256) void k_bin2(const int* __restrict__ src,
                                              const int* __restrict__ dst,
                                              int* __restrict__ cursorD,
                                              int* __restrict__ cursorS,
                                              unsigned* __restrict__ binbuf,
                                              unsigned* __restrict__ sbin) {
    __shared__ int cD[NBUCK], gD[NBUCK], aD[NBUCK];
    __shared__ int cS[NBUCK], gS[NBUCK], aS[NBUCK];
    const int base = blockIdx.x * CHUNK;
    const int end  = min(base + CHUNK, N_EDGES);
    for (int b = threadIdx.x; b < NBUCK; b += 256) {
        cD[b] = 0; aD[b] = 0; cS[b] = 0; aS[b] = 0;
    }
    __syncthreads();
    for (int e = base + threadIdx.x; e < end; e += 256) {
        atomicAdd(&cD[dst[e] >> BSHIFT], 1);
        atomicAdd(&cS[src[e] >> BSHIFT], 1);
    }
    __syncthreads();
    for (int b = threadIdx.x; b < NBUCK; b += 256) {
        if (cD[b] > 0) gD[b] = atomicAdd(&cursorD[b], cD[b]);
        if (cS[b] > 0) gS[b] = atomicAdd(&cursorS[b], cS[b]);
    }
    __syncthreads();
    for (int e = base + threadIdx.x; e < end; e += 256) {
        int d = dst[e], s = src[e];
        int bd = d >> BSHIFT;
        int od = atomicAdd(&aD[bd], 1);
        binbuf[gD[bd] + od] = ((unsigned)(d & (BNODES - 1)) << 17) | (unsigned)s;
        int bs = s >> BSHIFT;
        int os = atomicAdd(&aS[bs], 1);
        sbin[gS[bs] + os] = (unsigned)(s & (BNODES - 1));
    }
}

// ---------------- merged per-bucket histograms: normS, normD, row_ptr, ssrc --

__global__ __launch_bounds__(256) void k_hist_all(const unsigned* __restrict__ sbin,
                                                  const int* __restrict__ baseS,
                                                  const unsigned* __restrict__ binbuf,
                                                  const int* __restrict__ baseD,
                                                  float* __restrict__ normS,
                                                  float* __restrict__ normD,
                                                  int* __restrict__ row_ptr,
                                                  int* __restrict__ ssrc) {
    __shared__ int cnt[BNODES];
    __shared__ int tmp[BNODES];
    const int nodeBase = blockIdx.x << BSHIFT;
    // ---- src histogram -> normS
    for (int t = threadIdx.x; t < BNODES; t += 256) cnt[t] = 0;
    __syncthreads();
    {
        const int beg = baseS[blockIdx.x], end = baseS[blockIdx.x + 1];
        for (int e = beg + threadIdx.x; e < end; e += 256)
            atomicAdd(&cnt[sbin[e]], 1);
    }
    __syncthreads();
    for (int t = threadIdx.x; t < BNODES; t += 256) {
        int node = nodeBase + t;
        if (node < N_NODES)
            normS[node] = 1.0f / sqrtf((float)max(cnt[t], 1));
        cnt[t] = 0;                      // re-zero own slots for dst pass
    }
    __syncthreads();
    // ---- dst histogram -> normD + scan -> row_ptr + scatter ssrc
    const int beg = baseD[blockIdx.x], end = baseD[blockIdx.x + 1];
    for (int e = beg + threadIdx.x; e < end; e += 256)
        atomicAdd(&cnt[binbuf[e] >> 17], 1);
    __syncthreads();
    for (int t = threadIdx.x; t < BNODES; t += 256) {
        int node = nodeBase + t;
        if (node < N_NODES)
            normD[node] = 1.0f / sqrtf((float)max(cnt[t], 1));
    }
    // inclusive Hillis-Steele scan over cnt[512]
    for (int s = 1; s < BNODES; s <<= 1) {
        for (int t = threadIdx.x; t < BNODES; t += 256)
            tmp[t] = (t >= s) ? cnt[t - s] + cnt[t] : cnt[t];
        __syncthreads();
        for (int t = threadIdx.x; t < BNODES; t += 256) cnt[t] = tmp[t];
        __syncthreads();
    }
    for (int t = threadIdx.x; t < BNODES; t += 256) {
        int b = beg + ((t == 0) ? 0 : cnt[t - 1]);   // exclusive base
        tmp[t] = b;
        int node = nodeBase + t;
        if (node < N_NODES) row_ptr[node] = b;
    }
    if (blockIdx.x == 0 && threadIdx.x == 0) row_ptr[N_NODES] = N_EDGES;
    __syncthreads();
    for (int e = beg + threadIdx.x; e < end; e += 256) {
        unsigned v = binbuf[e];
        int pos = atomicAdd(&tmp[v >> 17], 1);
        ssrc[pos] = (int)(v & 0x1FFFFu);
    }
}

// ---------------- fused gather + GEMM (layer 1, small LDS: BKT1=16) --------
// out = relu((A_gather(X*normS) @ W) * normD + bias) * normS

#define BMT 64
#define BKT 32     // layer-2 standalone GEMM chunk
#define BKT1 16    // layer-1 fused chunk (smaller -> 25.6 KB LDS, 6 blk/CU)

__global__ __launch_bounds__(256) void k_fused1(const float* __restrict__ X,
                                                const int* __restrict__ row_ptr,
                                                const int* __restrict__ ssrc,
                                                const float* __restrict__ normS,
                                                const float* __restrict__ W,
                                                const float* __restrict__ normD,
                                                const float* __restrict__ bias,
                                                float* __restrict__ out) {
    __shared__ float xs[BMT][IN_DIM + 4];  // 64x68 = 17.4 KB
    __shared__ float ws[BKT1 * HID];       // 8 KB

    const int tid = threadIdx.x;
    const int rt = blockIdx.x * BMT;

    // ---- gather phase: 16 lanes per node, 16 nodes in flight
    {
        constexpr int LPN = IN_DIM / 4;    // 16
        constexpr int NCH = 256 / LPN;     // 16
        const int w = tid / LPN;
        const int lane = tid % LPN;
        const float4* __restrict__ hv = (const float4*)X;
        #pragma unroll
        for (int c = 0; c < BMT / NCH; ++c) {
            const int row = c * NCH + w;
            const int node = rt + row;
            float4 a4 = make_float4(0.f, 0.f, 0.f, 0.f);
            if (node < N_NODES) {
                const int beg = row_ptr[node], end = row_ptr[node + 1];
                int e = beg;
                for (; e + 4 <= end; e += 4) {
                    int s0 = ssrc[e + 0], s1 = ssrc[e + 1], s2 = ssrc[e + 2], s3 = ssrc[e + 3];
                    float n0 = normS[s0], n1 = normS[s1], n2 = normS[s2], n3 = normS[s3];
                    float4 v0 = hv[(size_t)s0 * LPN + lane];
                    float4 v1 = hv[(size_t)s1 * LPN + lane];
                    float4 v2 = hv[(size_t)s2 * LPN + lane];
                    float4 v3 = hv[(size_t)s3 * LPN + lane];
                    a4.x += v0.x * n0; a4.y += v0.y * n0; a4.z += v0.z * n0; a4.w += v0.w * n0;
                    a4.x += v1.x * n1; a4.y += v1.y * n1; a4.z += v1.z * n1; a4.w += v1.w * n1;
                    a4.x += v2.x * n2; a4.y += v2.y * n2; a4.z += v2.z * n2; a4.w += v2.w * n2;
                    a4.x += v3.x * n3; a4.y += v3.y * n3; a4.z += v3.z * n3; a4.w += v3.w * n3;
                }
                for (; e < end; ++e) {
                    int s0 = ssrc[e];
                    float n0 = normS[s0];
                    float4 v0 = hv[(size_t)s0 * LPN + lane];
                    a4.x += v0.x * n0; a4.y += v0.y * n0; a4.z += v0.z * n0; a4.w += v0.w * n0;
                }
            }
            *(float4*)&xs[row][lane * 4] = a4;
        }
    }

    // ---- GEMM phase (BKT1=16 chunks)
    const int tx = tid & 31;
    const int ty = tid >> 5;
    const int col0 = tx * 4;
    const int row0 = ty * 8;

    float acc[8][4];
    #pragma unroll
    for (int r = 0; r < 8; ++r)
        #pragma unroll
        for (int c = 0; c < 4; ++c) acc[r][c] = 0.f;

    for (int k0 = 0; k0 < IN_DIM; k0 += BKT1) {
        __syncthreads();
        {
            const float4* wsrc = (const float4*)(W + (size_t)k0 * HID);
            #pragma unroll
            for (int i = tid; i < BKT1 * HID / 4; i += 256)
                ((float4*)ws)[i] = wsrc[i];
        }
        __syncthreads();
        #pragma unroll 4
        for (int k = 0; k < BKT1; ++k) {
            float4 b = *(const float4*)&ws[k * HID + col0];
            float a[8];
            #pragma unroll
            for (int r = 0; r < 8; ++r) a[r] = xs[row0 + r][k0 + k];
            #pragma unroll
            for (int r = 0; r < 8; ++r) {
                acc[r][0] += a[r] * b.x;
                acc[r][1] += a[r] * b.y;
                acc[r][2] += a[r] * b.z;
                acc[r][3] += a[r] * b.w;
            }
        }
    }

    const float4 bb = *(const float4*)(bias + col0);
    #pragma unroll
    for (int r = 0; r < 8; ++r) {
        int gr = rt + row0 + r;
        if (gr < N_NODES) {
            float nd = normD[gr];
            float4 o;
            o.x = fmaxf(acc[r][0] * nd + bb.x, 0.f);
            o.y = fmaxf(acc[r][1] * nd + bb.y, 0.f);
            o.z = fmaxf(acc[r][2] * nd + bb.z, 0.f);
            o.w = fmaxf(acc[r][3] * nd + bb.w, 0.f);
            float ns = normS[gr];    // pre-apply next layer's src norm
            o.x *= ns; o.y *= ns; o.z *= ns; o.w *= ns;
            *(float4*)(out + (size_t)gr * HID + col0) = o;
        }
    }
}

// ---------------- layer-2 gather (zero-LDS, max occupancy) ----------------

#define ACC4(A, V) { A.x += V.x; A.y += V.y; A.z += V.z; A.w += V.w; }

__global__ __launch_bounds__(256) void k_agg128(const float* __restrict__ hs,
                                                const int* __restrict__ row_ptr,
                                                const int* __restrict__ ssrc,
                                                float* __restrict__ out) {
    const int node = blockIdx.x * 8 + (threadIdx.x >> 5);
    const int lane = threadIdx.x & 31;     // channels lane*4 .. lane*4+3 of 128
    if (node >= N_NODES) return;
    const int beg = row_ptr[node], end = row_ptr[node + 1];
    const float4* __restrict__ hv = (const float4*)hs;
    float4 acc = make_float4(0.f, 0.f, 0.f, 0.f);
    int e = beg;
    for (; e + 4 <= end; e += 4) {
        int s0 = ssrc[e + 0], s1 = ssrc[e + 1], s2 = ssrc[e + 2], s3 = ssrc[e + 3];
        float4 v0 = hv[(size_t)s0 * 32 + lane];
        float4 v1 = hv[(size_t)s1 * 32 + lane];
        float4 v2 = hv[(size_t)s2 * 32 + lane];
        float4 v3 = hv[(size_t)s3 * 32 + lane];
        ACC4(acc, v0); ACC4(acc, v1); ACC4(acc, v2); ACC4(acc, v3);
    }
    for (; e < end; ++e) {
        float4 v0 = hv[(size_t)ssrc[e] * 32 + lane];
        ACC4(acc, v0);
    }
    *(float4*)(out + (size_t)node * HID + lane * 4) = acc;
}

// ---------------- standalone register-tiled GEMM for layer 2 --------------
// out = relu((G @ W2) * normD + bias); keys = out[:,127]

__global__ __launch_bounds__(256) void k_gemm2(const float* __restrict__ X,
                                               const float* __restrict__ W,
                                               const float* __restrict__ normD,
                                               const float* __restrict__ bias,
                                               float* __restrict__ keys,
                                               float* __restrict__ out) {
    __shared__ float xs[BMT][BKT + 4];     // 64 x 36
    __shared__ float ws[BKT * HID];        // 16 KB

    const int tid = threadIdx.x;
    const int tx = tid & 31;
    const int ty = tid >> 5;
    const int col0 = tx * 4;
    const int row0 = ty * 8;
    const int rt = blockIdx.x * BMT;

    float acc[8][4];
    #pragma unroll
    for (int r = 0; r < 8; ++r)
        #pragma unroll
        for (int c = 0; c < 4; ++c) acc[r][c] = 0.f;

    for (int k0 = 0; k0 < HID; k0 += BKT) {
        __syncthreads();
        {
            const float4* wsrc = (const float4*)(W + (size_t)k0 * HID);
            #pragma unroll
            for (int i = tid; i < BKT * HID / 4; i += 256)
                ((float4*)ws)[i] = wsrc[i];
        }
        {
            #pragma unroll
            for (int i = tid; i < BMT * BKT / 4; i += 256) {
                int row = i >> 3;
                int kq  = i & 7;
                int gr  = rt + row;
                float4 v = make_float4(0.f, 0.f, 0.f, 0.f);
                if (gr < N_NODES)
                    v = *(const float4*)(X + (size_t)gr * HID + k0 + kq * 4);
                *(float4*)&xs[row][kq * 4] = v;
            }
        }
        __syncthreads();

        #pragma unroll 4
        for (int k = 0; k < BKT; ++k) {
            float4 b = *(const float4*)&ws[k * HID + col0];
            float a[8];
            #pragma unroll
            for (int r = 0; r < 8; ++r) a[r] = xs[row0 + r][k];
            #pragma unroll
            for (int r = 0; r < 8; ++r) {
                acc[r][0] += a[r] * b.x;
                acc[r][1] += a[r] * b.y;
                acc[r][2] += a[r] * b.z;
                acc[r][3] += a[r] * b.w;
            }
        }
    }

    const float4 bb = *(const float4*)(bias + col0);
    #pragma unroll
    for (int r = 0; r < 8; ++r) {
        int gr = rt + row0 + r;
        if (gr < N_NODES) {
            float nd = normD[gr];
            float4 o;
            o.x = fmaxf(acc[r][0] * nd + bb.x, 0.f);
            o.y = fmaxf(acc[r][1] * nd + bb.y, 0.f);
            o.z = fmaxf(acc[r][2] * nd + bb.z, 0.f);
            o.w = fmaxf(acc[r][3] * nd + bb.w, 0.f);
            if (col0 == 124) keys[gr] = o.w;   // channel 127
            *(float4*)(out + (size_t)gr * HID + col0) = o;
        }
    }
}

// ---------------- hybrid bitonic top-K (consolidated: 4 dispatches) --------
// Same comparator network as a full bitonic sort of SORTN u64 codes per graph
// (desc-mapped key<<32 | idx; pad sorts last). Stage-k direction for a span
// whose base is a multiple of k is uniform: up iff (base/k) even (within graph).

// stages k = 2..SORTC in LDS; loads keys directly (fold of old k_sort_init)
__global__ __launch_bounds__(1024) void k_sort_local0(const float* __restrict__ keys,
                                                      unsigned long long* __restrict__ arr) {
    __shared__ unsigned long long lds[SORTC];
    const int base  = blockIdx.x * SORTC;            // flat base into 8*16384
    const int gbase = base & (SORTN - 1);
    for (int idx = threadIdx.x; idx < SORTC; idx += 1024) {
        int gi = base + idx;
        int g = gi >> 14;                            // graph
        int l = gi & (SORTN - 1);                    // pos within graph
        unsigned long long c;
        if (l < NPER) {
            unsigned u = __float_as_uint(keys[g * NPER + l]);
            unsigned s = (u & 0x80000000u) ? ~u : (u | 0x80000000u); // asc map
            unsigned d = ~s;                                          // desc
            c = ((unsigned long long)d << 32) | (unsigned)l;
        } else {
            c = 0xFFFFFFFFFFFFFFFFull;
        }
        lds[idx] = c;
    }
    __syncthreads();
    for (int k = 2; k <= SORTC; k <<= 1) {
        for (int j = k >> 1; j > 0; j >>= 1) {
            int t = threadIdx.x;                     // SORTC/2 = 1024 CEs
            int i = ((t & ~(j - 1)) << 1) | (t & (j - 1));
            bool up = (((gbase + i) & k) == 0);
            unsigned long long a = lds[i], b = lds[i + j];
            if ((a > b) == up) { lds[i] = b; lds[i + j] = a; }
            __syncthreads();
        }
    }
    arr[base + threadIdx.x]        = lds[threadIdx.x];
    arr[base + threadIdx.x + 1024] = lds[threadIdx.x + 1024];
}

// one full stage k = SPAN, entirely in LDS (block spans SPAN elements)
template<int SPAN>
__global__ __launch_bounds__(1024) void k_sort_span(unsigned long long* __restrict__ arr) {
    __shared__ unsigned long long lds[SPAN];         // 32 KB or 64 KB
    const int base  = blockIdx.x * SPAN;
    const int gbase = base & (SORTN - 1);
    const bool up = ((gbase / SPAN) & 1) == 0;       // uniform within span
    for (int i = threadIdx.x; i < SPAN; i += 1024) lds[i] = arr[base + i];
    __syncthreads();
    for (int j = SPAN >> 1; j > 0; j >>= 1) {
        for (int t = threadIdx.x; t < SPAN / 2; t += 1024) {
            int i = ((t & ~(j - 1)) << 1) | (t & (j - 1));
            unsigned long long a = lds[i], b = lds[i + j];
            if ((a > b) == up) { lds[i] = b; lds[i + j] = a; }
        }
        __syncthreads();
    }
    for (int i = threadIdx.x; i < SPAN; i += 1024) arr[base + i] = lds[i];
}

// final stage k = SORTN: whole graph in 128 KB LDS; emits topk + bias-init
__global__ __launch_bounds__(1024) void k_sort_final16k(const unsigned long long* __restrict__ arr,
                                                        int* __restrict__ topk_idx,
                                                        const float* __restrict__ b3,
                                                        float* __restrict__ out) {
    __shared__ unsigned long long lds[SORTN];        // 128 KB (works: R1 k_topk)
    const int base = blockIdx.x * SORTN;             // one block per graph
    for (int i = threadIdx.x; i < SORTN; i += 1024) lds[i] = arr[base + i];
    __syncthreads();
    for (int j = SORTN >> 1; j > 0; j >>= 1) {       // up = true (ascending)
        for (int t = threadIdx.x; t < SORTN / 2; t += 1024) {
            int i = ((t & ~(j - 1)) << 1) | (t & (j - 1));
            unsigned long long a = lds[i], b = lds[i + j];
            if (a > b) { lds[i] = b; lds[i + j] = a; }
        }
        __syncthreads();
    }
    for (int i = threadIdx.x; i < TOPK; i += 1024)
        topk_idx[blockIdx.x * TOPK + i] = (int)(lds[i] & 0xFFFFFFFFull);
    if (blockIdx.x == 0 && threadIdx.x < BATCH * NCLS)
        out[threadIdx.x] = b3[threadIdx.x % NCLS];
}

// ---------------- final reduction GEMM ----------------

#define KPB 100   // top-k rows per block

__global__ __launch_bounds__(128) void k_final(const float* __restrict__ h2,
                                               const int* __restrict__ topk_idx,
                                               const float* __restrict__ W3,
                                               float* __restrict__ out) {
    __shared__ float red[128 * NCLS];
    const int b = blockIdx.x / (TOPK / KPB);
    const int chunk = blockIdx.x % (TOPK / KPB);
    const int j = threadIdx.x;
    float acc[NCLS];
    #pragma unroll
    for (int c = 0; c < NCLS; ++c) acc[c] = 0.f;
    const int k0 = chunk * KPB;
    for (int k = k0; k < k0 + KPB; ++k) {
        int node = b * NPER + topk_idx[b * TOPK + k];
        float h = h2[(size_t)node * HID + j];
        const float* wrow = W3 + (size_t)(k * HID + j) * NCLS;
        #pragma unroll
        for (int c = 0; c < NCLS; ++c) acc[c] += h * wrow[c];
    }
    #pragma unroll
    for (int c = 0; c < NCLS; ++c) red[j * NCLS + c] = acc[c];
    __syncthreads();
    for (int s = 64; s > 0; s >>= 1) {
        if (j < s) {
            #pragma unroll
            for (int c = 0; c < NCLS; ++c) red[j * NCLS + c] += red[(j + s) * NCLS + c];
        }
        __syncthreads();
    }
    if (j < NCLS) atomicAdd(&out[b * NCLS + j], red[j]);
}

// ---------------- launch ----------------

extern "C" void kernel_launch(void* const* d_in, const int* in_sizes, int n_in,
                              void* d_out, int out_size, void* d_ws, size_t ws_size,
                              hipStream_t stream) {
    const float* features = (const float*)d_in[0];
    const int*   src      = (const int*)d_in[1];
    const int*   dst      = (const int*)d_in[2];
    const float* W1       = (const float*)d_in[3];
    const float* b1       = (const float*)d_in[4];
    const float* W2       = (const float*)d_in[5];
    const float* b2       = (const float*)d_in[6];
    const float* W3       = (const float*)d_in[7];
    const float* b3       = (const float*)d_in[8];
    float* out = (float*)d_out;

    char* p = (char*)d_ws;
    auto carve = [&](size_t bytes) -> void* {
        void* r = (void*)p;
        p += (bytes + 511) & ~(size_t)511;
        return r;
    };
    float* normS     = (float*)carve((size_t)N_NODES * 4);
    float* normD     = (float*)carve((size_t)N_NODES * 4);
    int*   row_ptr   = (int*)carve((size_t)(N_NODES + 1) * 4);
    int*   bcntS     = (int*)carve((size_t)NBUCK * 4);
    int*   bcntD     = (int*)carve((size_t)NBUCK * 4);
    int*   baseS     = (int*)carve((size_t)(NBUCK + 1) * 4);
    int*   baseD     = (int*)carve((size_t)(NBUCK + 1) * 4);
    int*   curS      = (int*)carve((size_t)NBUCK * 4);
    int*   curD      = (int*)carve((size_t)NBUCK * 4);
    int*   ssrc      = (int*)carve((size_t)N_EDGES * 4);
    unsigned* binbuf = (unsigned*)carve((size_t)N_EDGES * 4);
    unsigned* sbin   = (unsigned*)carve((size_t)N_EDGES * 4);
    float* keys      = (float*)carve((size_t)N_NODES * 4);
    int*   topk_idx  = (int*)carve((size_t)BATCH * TOPK * 4);
    unsigned long long* sortbuf = (unsigned long long*)carve((size_t)BATCH * SORTN * 8);
    float* bufA      = (float*)carve((size_t)N_NODES * HID * 4);   // h1s, then h2
    float* bufB      = (float*)carve((size_t)N_NODES * HID * 4);   // g2

    const int GB = (N_NODES + BMT - 1) / BMT;     // 1563 tiles
    const int BB = (N_EDGES + CHUNK - 1) / CHUNK; // bin blocks (196)

    hipMemsetAsync(bcntS, 0, (size_t)NBUCK * 4, stream);
    hipMemsetAsync(bcntD, 0, (size_t)NBUCK * 4, stream);

    // CSR build + degrees/norms via bucket binning (no global scatter atomics)
    k_bcount<<<BB, 256, 0, stream>>>(src, dst, bcntS, bcntD);
    k_bscan<<<1, 64, 0, stream>>>(bcntS, bcntD, baseS, baseD, curS, curD);
    k_bin2<<<BB, 256, 0, stream>>>(src, dst, curD, curS, binbuf, sbin);
    k_hist_all<<<NBUCK, 256, 0, stream>>>(sbin, baseS, binbuf, baseD,
                                          normS, normD, row_ptr, ssrc);

    // layer 1: fused gather(64ch) + W1 GEMM + epilogue (25.6 KB LDS, 6 blk/CU)
    k_fused1<<<GB, 256, 0, stream>>>(features, row_ptr, ssrc, normS, W1, normD, b1, bufA);
    // layer 2: zero-LDS gather at full occupancy, then GEMM
    k_agg128<<<(N_NODES + 7) / 8, 256, 0, stream>>>(bufA, row_ptr, ssrc, bufB);
    k_gemm2<<<GB, 256, 0, stream>>>(bufB, W2, normD, b2, keys, bufA);

    // hybrid bitonic full sort, consolidated to 4 dispatches
    k_sort_local0<<<BATCH * SORTN / SORTC, 1024, 0, stream>>>(keys, sortbuf);      // 64 blk
    k_sort_span<4096><<<BATCH * SORTN / 4096, 1024, 0, stream>>>(sortbuf);         // 32 blk
    k_sort_span<8192><<<BATCH * SORTN / 8192, 1024, 0, stream>>>(sortbuf);         // 16 blk
    k_sort_final16k<<<BATCH, 1024, 0, stream>>>(sortbuf, topk_idx, b3, out);       //  8 blk

    k_final<<<BATCH * (TOPK / KPB), 128, 0, stream>>>(bufA, topk_idx, W3, out);
}